// Round 11
// baseline (198.727 us; speedup 1.0000x reference)
//
#include <hip/hip_runtime.h>
#include <stdint.h>

typedef _Float16 f16;
typedef _Float16 f16x8 __attribute__((ext_vector_type(8)));
typedef _Float16 f16x4 __attribute__((ext_vector_type(4)));
typedef __fp16   h16x2 __attribute__((ext_vector_type(2)));
typedef float    f32x4 __attribute__((ext_vector_type(4)));

#define MFMA_F16(A, B, C) __builtin_amdgcn_mfma_f32_16x16x32_f16((A), (B), (C), 0, 0, 0)

__device__ __forceinline__ void gload_lds16(const void* g, void* l) {
  __builtin_amdgcn_global_load_lds((const __attribute__((address_space(1))) void*)g,
                                   (__attribute__((address_space(3))) void*)l, 16, 0, 0);
}

// ---------------------------------------------------------------- f32 -> f16 converts (weights only)
__global__ void cvt_f32_f16(const float* __restrict__ s0, const float* __restrict__ s1,
                            const float* __restrict__ s2, const float* __restrict__ s3,
                            f16* __restrict__ d0, f16* __restrict__ d1,
                            f16* __restrict__ d2, f16* __restrict__ d3) {
  const float* sp; f16* dp;
  switch (blockIdx.y) {
    case 0:  sp = s0; dp = d0; break;
    case 1:  sp = s1; dp = d1; break;
    case 2:  sp = s2; dp = d2; break;
    default: sp = s3; dp = d3; break;
  }
  const int n4 = (1024 * 1024) / 4;
  int stride = gridDim.x * blockDim.x;
  for (int i = blockIdx.x * blockDim.x + threadIdx.x; i < n4; i += stride) {
    f32x4 v = *(const f32x4*)(sp + (size_t)i * 4);
    f16x4 h;
    h[0] = (f16)v[0]; h[1] = (f16)v[1]; h[2] = (f16)v[2]; h[3] = (f16)v[3];
    *(f16x4*)(dp + (size_t)i * 4) = h;
  }
}

// ---------------------------------------------------------------- GEMM core (K=1024, 128x128 tile,
// BK=32, THREE LDS buffers, depth-2 prefetch, counted vmcnt(4) — used by out_gemm (round-8 proven).
__device__ __forceinline__ void gemm_core_k1024(const f16* __restrict__ A, const f16* __restrict__ W,
                                                f16* lA, f16* lB, f32x4 (&acc)[4][4],
                                                int row0, int col0) {
  const int tid = threadIdx.x;
  const int lane = tid & 63;
  const int w = tid >> 6;
  const int g = lane >> 4, c = lane & 15;
  const int wr = (w >> 1) * 64, wc = (w & 1) * 64;

  int sr[2], scol[2];
#pragma unroll
  for (int p = 0; p < 2; ++p) {
    int slot = p * 256 + tid;
    int r = slot >> 2, sph = slot & 3;
    sr[p] = r;
    scol[p] = (sph ^ ((r >> 1) & 3)) * 8;
  }
  const f16* Abase = A + (size_t)row0 * 1024;
  const f16* Wbase = W + (size_t)col0 * 1024;

  auto STAGE = [&](int nb, int k0) {
#pragma unroll
    for (int p = 0; p < 2; ++p) {
      gload_lds16(Abase + (size_t)sr[p] * 1024 + k0 + scol[p],
                  lA + nb * (128 * 32) + (p * 256 + w * 64) * 8);
      gload_lds16(Wbase + (size_t)sr[p] * 1024 + k0 + scol[p],
                  lB + nb * (128 * 32) + (p * 256 + w * 64) * 8);
    }
  };

  STAGE(0, 0);
  STAGE(1, 32);

  int cur = 0;
  for (int kt = 0; kt < 32; ++kt) {
    if (kt < 31) {
      asm volatile("s_waitcnt vmcnt(4)" ::: "memory");
    } else {
      asm volatile("s_waitcnt vmcnt(0)" ::: "memory");
    }
    __builtin_amdgcn_s_barrier();
    __builtin_amdgcn_sched_barrier(0);
    if (kt < 30) {
      int nxt2 = (cur >= 1) ? cur - 1 : 2;
      STAGE(nxt2, (kt + 2) * 32);
    }

    const f16* cA = lA + cur * (128 * 32);
    const f16* cB = lB + cur * (128 * 32);
    f16x8 af[4], bf[4];
#pragma unroll
    for (int m = 0; m < 4; ++m) {
      int r = wr + m * 16 + c;
      af[m] = *(const f16x8*)(cA + r * 32 + (g ^ ((r >> 1) & 3)) * 8);
    }
#pragma unroll
    for (int n = 0; n < 4; ++n) {
      int r = wc + n * 16 + c;
      bf[n] = *(const f16x8*)(cB + r * 32 + (g ^ ((r >> 1) & 3)) * 8);
    }
    __builtin_amdgcn_s_setprio(1);
#pragma unroll
    for (int m = 0; m < 4; ++m)
#pragma unroll
      for (int n = 0; n < 4; ++n)
        acc[m][n] = MFMA_F16(af[m], bf[n], acc[m][n]);
    __builtin_amdgcn_s_setprio(0);

    cur = (cur < 2) ? cur + 1 : 0;
  }
}

// ---------------------------------------------------------------- pair-fused projections with FUSED
// f32->f16 A-conversion (reg-staged A: global f32 loads -> cvt_pkrtz -> ds_write_b128 into the
// same swizzled layout; B panels via global_load_lds as before). Depth-1 double-buffer.
// Pair 0 (XCDs 0-3): A=src -> q AND v_src. Pair 1 (XCDs 4-7): A=tgt -> k AND v_tgt.
// v stored transposed [(b*16+h)*64+d][1024] with t pre-permuted for attn b128 reads.
__global__ __launch_bounds__(256, 2) void proj_gemm(
    const float* __restrict__ srcF, const float* __restrict__ tgtF,
    const f16* __restrict__ qw16, const f16* __restrict__ kw16, const f16* __restrict__ vw16,
    const float* __restrict__ qb, const float* __restrict__ kb, const float* __restrict__ vb,
    f16* __restrict__ q16, f16* __restrict__ k16, f16* __restrict__ vtS, f16* __restrict__ vtT) {
  __shared__ f16 lA[2 * 128 * 32];
  __shared__ f16 lB1[2 * 128 * 32];
  __shared__ f16 lB2[2 * 128 * 32];
  const int lin = blockIdx.x;               // 512 blocks
  const int xcd = lin & 7;
  const int slot = lin >> 3;                // 0..63
  const int pr = xcd >> 2;                  // 0..1 (4 XCDs per pair)
  const int y = (xcd & 3) * 8 + (slot >> 3);  // 0..31
  const int x = slot & 7;                   // 0..7

  const float* A = pr ? tgtF : srcF;
  const f16* W1 = pr ? kw16 : qw16;
  const float* b1 = pr ? kb : qb;
  f16* O1 = pr ? k16 : q16;
  f16* O2 = pr ? vtT : vtS;
  const int row0 = y * 128;
  const int col0 = x * 128;

  const int tid = threadIdx.x;
  const int lane = tid & 63;
  const int w = tid >> 6;
  const int g = lane >> 4, c = lane & 15;
  const int wr = (w >> 1) * 64, wc = (w & 1) * 64;

  int sr[2], scol[2];
#pragma unroll
  for (int p = 0; p < 2; ++p) {
    int slt = p * 256 + tid;
    int r = slt >> 2, sph = slt & 3;
    sr[p] = r;
    scol[p] = (sph ^ ((r >> 1) & 3)) * 8;
  }
  const float* Abase = A + (size_t)row0 * 1024;
  const f16* W1base = W1 + (size_t)col0 * 1024;
  const f16* W2base = vw16 + (size_t)col0 * 1024;

  f32x4 areg[2][2];

  auto LOADA = [&](int k0) {
#pragma unroll
    for (int p = 0; p < 2; ++p) {
      const float* ap = Abase + (size_t)sr[p] * 1024 + k0 + scol[p];
      areg[p][0] = *(const f32x4*)ap;
      areg[p][1] = *(const f32x4*)(ap + 4);
    }
  };
  auto WRITEA = [&](int nb) {
#pragma unroll
    for (int p = 0; p < 2; ++p) {
      union { f16x8 v; h16x2 h[4]; } u;
      u.h[0] = __builtin_amdgcn_cvt_pkrtz(areg[p][0][0], areg[p][0][1]);
      u.h[1] = __builtin_amdgcn_cvt_pkrtz(areg[p][0][2], areg[p][0][3]);
      u.h[2] = __builtin_amdgcn_cvt_pkrtz(areg[p][1][0], areg[p][1][1]);
      u.h[3] = __builtin_amdgcn_cvt_pkrtz(areg[p][1][2], areg[p][1][3]);
      *(f16x8*)(lA + nb * (128 * 32) + (p * 256 + tid) * 8) = u.v;  // ds_write_b128
    }
  };
  auto STAGEB = [&](int nb, int k0) {
#pragma unroll
    for (int p = 0; p < 2; ++p) {
      gload_lds16(W1base + (size_t)sr[p] * 1024 + k0 + scol[p],
                  lB1 + nb * (128 * 32) + (p * 256 + w * 64) * 8);
      gload_lds16(W2base + (size_t)sr[p] * 1024 + k0 + scol[p],
                  lB2 + nb * (128 * 32) + (p * 256 + w * 64) * 8);
    }
  };

  f32x4 acc1[4][4] = {};
  f32x4 acc2[4][4] = {};

  LOADA(0);
  STAGEB(0, 0);

  for (int kt = 0; kt < 32; ++kt) {
    const int cur = kt & 1;
    asm volatile("s_waitcnt vmcnt(0)" ::: "memory");   // A regs (kt) + B lds (kt) landed
    WRITEA(cur);                                       // convert + ds_write A(kt)
    if (kt < 31) LOADA((kt + 1) * 32);                 // issue next A loads
    asm volatile("s_waitcnt lgkmcnt(0)" ::: "memory"); // A ds_writes done before barrier
    __builtin_amdgcn_s_barrier();                      // lA[cur]+lB[cur] ready block-wide
    __builtin_amdgcn_sched_barrier(0);
    if (kt < 31) STAGEB(cur ^ 1, (kt + 1) * 32);       // B(kt+1) flies under compute(kt)

    const f16* cA = lA + cur * (128 * 32);
    const f16* cB1 = lB1 + cur * (128 * 32);
    const f16* cB2 = lB2 + cur * (128 * 32);
    f16x8 af[4], bf1[4], bf2[4];
#pragma unroll
    for (int m = 0; m < 4; ++m) {
      int r = wr + m * 16 + c;
      af[m] = *(const f16x8*)(cA + r * 32 + (g ^ ((r >> 1) & 3)) * 8);
    }
#pragma unroll
    for (int n = 0; n < 4; ++n) {
      int r = wc + n * 16 + c;
      int off = r * 32 + (g ^ ((r >> 1) & 3)) * 8;
      bf1[n] = *(const f16x8*)(cB1 + off);
      bf2[n] = *(const f16x8*)(cB2 + off);
    }
    __builtin_amdgcn_s_setprio(1);
#pragma unroll
    for (int m = 0; m < 4; ++m)
#pragma unroll
      for (int n = 0; n < 4; ++n) {
        acc1[m][n] = MFMA_F16(af[m], bf1[n], acc1[m][n]);
        acc2[m][n] = MFMA_F16(af[m], bf2[n], acc2[m][n]);
      }
    __builtin_amdgcn_s_setprio(0);
  }

  // epilogue 1: q/k row-major
#pragma unroll
  for (int n = 0; n < 4; ++n) {
    int colg = col0 + wc + n * 16 + c;
    float bv = b1[colg];
#pragma unroll
    for (int m = 0; m < 4; ++m) {
      int rb = row0 + wr + m * 16 + g * 4;
#pragma unroll
      for (int r = 0; r < 4; ++r)
        O1[(size_t)(rb + r) * 1024 + colg] = (f16)(acc1[m][n][r] + bv);
    }
  }
  // epilogue 2: v transposed + t-permuted
#pragma unroll
  for (int n = 0; n < 4; ++n) {
    int colg = col0 + wc + n * 16 + c;   // = h*64 + d
    float bv = vb[colg];
#pragma unroll
    for (int m = 0; m < 4; ++m) {
      int row = row0 + wr + m * 16 + g * 4;   // token row (b*1024 + t), r = +0..3
      int bb = row >> 10, t = row & 1023;
      int tl = t & 63;
      int tp = (t & ~63) + (tl & 32) + ((tl & 12) << 1) + ((tl & 16) >> 2) + (tl & 3);
      f16x4 pk;
#pragma unroll
      for (int r = 0; r < 4; ++r) pk[r] = (f16)(acc2[m][n][r] + bv);
      *(f16x4*)(O2 + ((size_t)(bb << 10) + colg) * 1024 + tp) = pk;  // 8B store
    }
  }
}

// ---------------------------------------------------------------- output projection (f32 out)
// grid = 512: xcd = lin&7, slot = lin>>3 (0..63); y = xcd*8 + slot>>3 (0..63), x = slot&7
__global__ __launch_bounds__(256, 2) void out_gemm(
    const f16* __restrict__ opre, const f16* __restrict__ ow16,
    const float* __restrict__ ob, float* __restrict__ out) {
  __shared__ f16 lA[3 * 128 * 32];
  __shared__ f16 lB[3 * 128 * 32];
  const int lin = blockIdx.x;
  const int xcd = lin & 7;
  const int slot = lin >> 3;                // 0..63
  const int y = xcd * 8 + (slot >> 3);      // 0..63
  const int x = slot & 7;                   // 0..7
  const int row0 = y * 128;
  const int col0 = x * 128;
  f32x4 acc[4][4] = {};
  gemm_core_k1024(opre, ow16, lA, lB, acc, row0, col0);
  const int lane = threadIdx.x & 63;
  const int w = threadIdx.x >> 6;
  const int g = lane >> 4, c = lane & 15;
  const int wr = (w >> 1) * 64, wc = (w & 1) * 64;
#pragma unroll
  for (int n = 0; n < 4; ++n) {
    int colg = col0 + wc + n * 16 + c;
    float bv = ob[colg];
#pragma unroll
    for (int m = 0; m < 4; ++m) {
      int rb = row0 + wr + m * 16 + g * 4;
#pragma unroll
      for (int r = 0; r < 4; ++r)
        out[(size_t)(rb + r) * 1024 + colg] = acc[m][n][r] + bv;
    }
  }
}

// ---------------------------------------------------------------- fused 2-pass flash attention
// 64 q-rows/wave, swapped QK^T, no-max exp2 softmax, deferred l-reduce, XOR-swizzled staging,
// XCD decode, setprio, pkrtz P-pack. NEW: KV tile 128 (two 64-wide sub-steps per staged tile)
// -> 8 barriers instead of 16, double the latency-hiding window per stage. LDS 64 KB, 2 blk/CU.
__global__ __launch_bounds__(256, 2) void attn_fwd(
    const f16* __restrict__ q16, const f16* __restrict__ k16,
    const f16* __restrict__ vtS, const f16* __restrict__ vtT,
    const int* __restrict__ smask, const int* __restrict__ tmask,
    f16* __restrict__ opre) {
  const int bid = blockIdx.x;
  const int xcd = bid & 7;
  const int idx = bid >> 3;                 // 0..63
  const int bhp = xcd * 16 + (idx >> 2);    // 0..127 (16 contiguous per XCD)
  const int qblk = idx & 3;                 // 0..3
  const int pass = bhp >> 6;
  const int bh = bhp & 63;
  const int b = bh >> 4, h = bh & 15;

  const f16* Q  = pass ? k16 : q16;
  const f16* Kt = pass ? q16 : k16;
  const f16* VT = pass ? vtS : vtT;
  const int* qmask = pass ? tmask : smask;
  const int outRowOff = pass ? 4096 : 0;

  const int tid = threadIdx.x;
  const int lane = tid & 63, wv = tid >> 6;
  const int g = lane >> 4, c = lane & 15;
  const int qrow0 = qblk * 256 + wv * 64;   // 64 q-rows per wave

  __shared__ f16 lK[2][128 * 64];           // [t-local 0..127][d 8 units, XOR-swizzled]
  __shared__ f16 lV[2][64 * 128];           // [d-local 0..63][t 16 units, XOR-swizzled]

  const size_t kbase = (size_t)b * (1024 * 1024) + h * 64;
  const size_t vbase = (size_t)bh * (64 * 1024);

  const float SC2 = 0.18033688f;  // 0.125 * log2(e)
  f16x8 qf[4][2];
#pragma unroll
  for (int m = 0; m < 4; ++m) {
    f16 sh = (f16)(qmask[b * 1024 + qrow0 + m * 16 + c] ? SC2 : 0.0f);
#pragma unroll
    for (int kc = 0; kc < 2; ++kc) {
      f16x8 v = *(const f16x8*)(Q + ((size_t)(b * 1024 + qrow0 + m * 16 + c)) * 1024 + h * 64 + kc * 32 + g * 8);
#pragma unroll
      for (int j = 0; j < 8; ++j) v[j] *= sh;
      qf[m][kc] = v;
    }
  }

  // 1024 16B-slots per 128-tile per matrix; thread covers p = i*256 + tid (i=0..3).
  // K: slot p -> (row = p>>3, pc = p&7), holds global d-unit u = pc ^ (row&7).
  // V: slot p -> (row = p>>4, pc = p&15), holds global t-unit u = pc ^ (row&7).
  auto STAGE = [&](int nb, int t0) {
#pragma unroll
    for (int i = 0; i < 4; ++i) {
      int p = i * 256 + tid;
      int rowK = p >> 3;
      int uK = (p & 7) ^ (rowK & 7);
      gload_lds16(Kt + kbase + (size_t)(t0 + rowK) * 1024 + uK * 8, &lK[nb][(i * 256 + wv * 64) * 8]);
      int rowV = p >> 4;
      int uV = (p & 15) ^ (rowV & 7);
      gload_lds16(VT + vbase + (size_t)rowV * 1024 + t0 + uV * 8, &lV[nb][(i * 256 + wv * 64) * 8]);
    }
  };

  f32x4 accO[4][4] = {};
  float lpart[4] = {0.0f, 0.0f, 0.0f, 0.0f};

  STAGE(0, 0);

  for (int tt = 0; tt < 8; ++tt) {
    asm volatile("s_waitcnt vmcnt(0)" ::: "memory");
    __builtin_amdgcn_s_barrier();
    __builtin_amdgcn_sched_barrier(0);
    if (tt < 7) STAGE((tt + 1) & 1, (tt + 1) * 128);
    const f16* curK = lK[tt & 1];
    const f16* curV = lV[tt & 1];

#pragma unroll
    for (int ts = 0; ts < 2; ++ts) {
      // K fragments (A-operand): t-local row = ts*64 + n*16 + c
      f16x8 kf[4][2];
#pragma unroll
      for (int n = 0; n < 4; ++n) {
        int row = ts * 64 + n * 16 + c;
#pragma unroll
        for (int kc = 0; kc < 2; ++kc)
          kf[n][kc] = *(const f16x8*)(curK + row * 64 + (((kc * 4 + g) ^ (row & 7)) * 8));
      }

      // V fragments (B-operand): d row = nd*16+c, t-units at ts*8 + swizzled
      f16x8 vf[4][2];
#pragma unroll
      for (int nd = 0; nd < 4; ++nd) {
        int row = nd * 16 + c;
#pragma unroll
        for (int kc = 0; kc < 2; ++kc)
          vf[nd][kc] = *(const f16x8*)(curV + row * 128 + ((ts * 8 + ((kc * 4 + g) ^ (row & 7))) * 8));
      }

      f16x8 pa[4][2];
#pragma unroll
      for (int m = 0; m < 4; ++m) {
        f32x4 sc[4];
        __builtin_amdgcn_s_setprio(1);
#pragma unroll
        for (int n = 0; n < 4; ++n) {
          f32x4 z = {0.0f, 0.0f, 0.0f, 0.0f};
          z = MFMA_F16(kf[n][0], qf[m][0], z);
          sc[n] = MFMA_F16(kf[n][1], qf[m][1], z);
        }
        __builtin_amdgcn_s_setprio(0);
        float e[16];
#pragma unroll
        for (int n = 0; n < 4; ++n)
#pragma unroll
          for (int r = 0; r < 4; ++r) e[n * 4 + r] = __builtin_amdgcn_exp2f(sc[n][r]);
        float s8[8];
#pragma unroll
        for (int i = 0; i < 8; ++i) s8[i] = e[i] + e[i + 8];
        float s4[4];
#pragma unroll
        for (int i = 0; i < 4; ++i) s4[i] = s8[i] + s8[i + 4];
        lpart[m] += (s4[0] + s4[1]) + (s4[2] + s4[3]);
        union PU { f16x8 v; h16x2 h[4]; } u0, u1;
#pragma unroll
        for (int i = 0; i < 4; ++i) {
          u0.h[i] = __builtin_amdgcn_cvt_pkrtz(e[2 * i], e[2 * i + 1]);
          u1.h[i] = __builtin_amdgcn_cvt_pkrtz(e[8 + 2 * i], e[9 + 2 * i]);
        }
        pa[m][0] = u0.v;
        pa[m][1] = u1.v;
      }

      __builtin_amdgcn_s_setprio(1);
#pragma unroll
      for (int m = 0; m < 4; ++m)
#pragma unroll
        for (int nd = 0; nd < 4; ++nd) {
          accO[m][nd] = MFMA_F16(pa[m][0], vf[nd][0], accO[m][nd]);
          accO[m][nd] = MFMA_F16(pa[m][1], vf[nd][1], accO[m][nd]);
        }
      __builtin_amdgcn_s_setprio(0);
    }
  }

  // epilogue: complete l across lanes, then O[q][d] / l(q)
#pragma unroll
  for (int m = 0; m < 4; ++m) {
    float ls = lpart[m];
    ls += __shfl_xor(ls, 16);
    ls += __shfl_xor(ls, 32);
#pragma unroll
    for (int r = 0; r < 4; ++r) {
      float lr = __shfl(ls, 20 * g + r);
      float inv = 1.0f / lr;
      size_t orow = (size_t)(outRowOff + b * 1024 + qrow0 + m * 16 + 4 * g + r);
#pragma unroll
      for (int nd = 0; nd < 4; ++nd)
        opre[orow * 1024 + h * 64 + nd * 16 + c] = (f16)(accO[m][nd][r] * inv);
    }
  }
}

// ---------------------------------------------------------------- launcher
extern "C" void kernel_launch(void* const* d_in, const int* in_sizes, int n_in,
                              void* d_out, int out_size, void* d_ws, size_t ws_size,
                              hipStream_t stream) {
  (void)in_sizes; (void)n_in; (void)out_size; (void)ws_size;
  const float* src = (const float*)d_in[0];
  const float* tgt = (const float*)d_in[1];
  const int*   smask = (const int*)d_in[2];
  const int*   tmask = (const int*)d_in[3];
  const float* qw = (const float*)d_in[4];
  const float* qb = (const float*)d_in[5];
  const float* kw = (const float*)d_in[6];
  const float* kb = (const float*)d_in[7];
  const float* vw = (const float*)d_in[8];
  const float* vb = (const float*)d_in[9];
  const float* ow = (const float*)d_in[10];
  const float* ob = (const float*)d_in[11];
  float* out = (float*)d_out;

  f16* wsp = (f16*)d_ws;
  const size_t M4 = (size_t)4096 * 1024;
  const size_t M1 = (size_t)1024 * 1024;
  f16* opre  = wsp;                 // [0, 8M) f16
  f16* qw16  = wsp + 2 * M4;        // 8M
  f16* kw16  = qw16 + M1;           // 9M
  f16* vw16  = kw16 + M1;           // 10M
  f16* ow16  = vw16 + M1;           // 11M
  f16* q16   = ow16 + M1;           // 12M
  f16* k16   = q16 + M4;            // 16M
  f16* vtS   = k16 + M4;            // 20M
  f16* vtT   = vtS + M4;            // 24M..28M

  cvt_f32_f16<<<dim3(256, 4), 256, 0, stream>>>(qw, kw, vw, ow, qw16, kw16, vw16, ow16);
  proj_gemm<<<dim3(512), 256, 0, stream>>>(src, tgt, qw16, kw16, vw16,
                                           qb, kb, vb, q16, k16, vtS, vtT);
  attn_fwd<<<dim3(512), 256, 0, stream>>>(q16, k16, vtS, vtT, smask, tmask, opre);
  out_gemm<<<dim3(512), 256, 0, stream>>>(opre, ow16, ob, out);
}

// Round 12
// 118.550 us; speedup vs baseline: 1.6763x; 1.6763x over previous
//
#include <hip/hip_runtime.h>
#include <stdint.h>

typedef _Float16 f16;
typedef _Float16 f16x8 __attribute__((ext_vector_type(8)));
typedef _Float16 f16x4 __attribute__((ext_vector_type(4)));
typedef __fp16   h16x2 __attribute__((ext_vector_type(2)));
typedef float    f32x4 __attribute__((ext_vector_type(4)));

#define MFMA_F16(A, B, C) __builtin_amdgcn_mfma_f32_16x16x32_f16((A), (B), (C), 0, 0, 0)

__device__ __forceinline__ void gload_lds16(const void* g, void* l) {
  __builtin_amdgcn_global_load_lds((const __attribute__((address_space(1))) void*)g,
                                   (__attribute__((address_space(3))) void*)l, 16, 0, 0);
}

// ---------------------------------------------------------------- f32 -> f16 converts (weights only)
__global__ void cvt_f32_f16(const float* __restrict__ s0, const float* __restrict__ s1,
                            const float* __restrict__ s2, const float* __restrict__ s3,
                            f16* __restrict__ d0, f16* __restrict__ d1,
                            f16* __restrict__ d2, f16* __restrict__ d3) {
  const float* sp; f16* dp;
  switch (blockIdx.y) {
    case 0:  sp = s0; dp = d0; break;
    case 1:  sp = s1; dp = d1; break;
    case 2:  sp = s2; dp = d2; break;
    default: sp = s3; dp = d3; break;
  }
  const int n4 = (1024 * 1024) / 4;
  int stride = gridDim.x * blockDim.x;
  for (int i = blockIdx.x * blockDim.x + threadIdx.x; i < n4; i += stride) {
    f32x4 v = *(const f32x4*)(sp + (size_t)i * 4);
    f16x4 h;
    h[0] = (f16)v[0]; h[1] = (f16)v[1]; h[2] = (f16)v[2]; h[3] = (f16)v[3];
    *(f16x4*)(dp + (size_t)i * 4) = h;
  }
}

// ---------------------------------------------------------------- GEMM core (K=1024, 128x128 tile,
// BK=32, THREE LDS buffers, depth-2 prefetch, counted vmcnt(4) — used by out_gemm (round-8 proven).
__device__ __forceinline__ void gemm_core_k1024(const f16* __restrict__ A, const f16* __restrict__ W,
                                                f16* lA, f16* lB, f32x4 (&acc)[4][4],
                                                int row0, int col0) {
  const int tid = threadIdx.x;
  const int lane = tid & 63;
  const int w = tid >> 6;
  const int g = lane >> 4, c = lane & 15;
  const int wr = (w >> 1) * 64, wc = (w & 1) * 64;

  int sr[2], scol[2];
#pragma unroll
  for (int p = 0; p < 2; ++p) {
    int slot = p * 256 + tid;
    int r = slot >> 2, sph = slot & 3;
    sr[p] = r;
    scol[p] = (sph ^ ((r >> 1) & 3)) * 8;
  }
  const f16* Abase = A + (size_t)row0 * 1024;
  const f16* Wbase = W + (size_t)col0 * 1024;

  auto STAGE = [&](int nb, int k0) {
#pragma unroll
    for (int p = 0; p < 2; ++p) {
      gload_lds16(Abase + (size_t)sr[p] * 1024 + k0 + scol[p],
                  lA + nb * (128 * 32) + (p * 256 + w * 64) * 8);
      gload_lds16(Wbase + (size_t)sr[p] * 1024 + k0 + scol[p],
                  lB + nb * (128 * 32) + (p * 256 + w * 64) * 8);
    }
  };

  STAGE(0, 0);
  STAGE(1, 32);

  int cur = 0;
  for (int kt = 0; kt < 32; ++kt) {
    if (kt < 31) {
      asm volatile("s_waitcnt vmcnt(4)" ::: "memory");
    } else {
      asm volatile("s_waitcnt vmcnt(0)" ::: "memory");
    }
    __builtin_amdgcn_s_barrier();
    __builtin_amdgcn_sched_barrier(0);
    if (kt < 30) {
      int nxt2 = (cur >= 1) ? cur - 1 : 2;
      STAGE(nxt2, (kt + 2) * 32);
    }

    const f16* cA = lA + cur * (128 * 32);
    const f16* cB = lB + cur * (128 * 32);
    f16x8 af[4], bf[4];
#pragma unroll
    for (int m = 0; m < 4; ++m) {
      int r = wr + m * 16 + c;
      af[m] = *(const f16x8*)(cA + r * 32 + (g ^ ((r >> 1) & 3)) * 8);
    }
#pragma unroll
    for (int n = 0; n < 4; ++n) {
      int r = wc + n * 16 + c;
      bf[n] = *(const f16x8*)(cB + r * 32 + (g ^ ((r >> 1) & 3)) * 8);
    }
    __builtin_amdgcn_s_setprio(1);
#pragma unroll
    for (int m = 0; m < 4; ++m)
#pragma unroll
      for (int n = 0; n < 4; ++n)
        acc[m][n] = MFMA_F16(af[m], bf[n], acc[m][n]);
    __builtin_amdgcn_s_setprio(0);

    cur = (cur < 2) ? cur + 1 : 0;
  }
}

// ---------------------------------------------------------------- pair-fused projections with FUSED
// f32->f16 A-conversion (reg-staged A -> cvt_pkrtz -> ds_write_b128 swizzled; B via global_load_lds).
// Pair 0 (XCDs 0-3): A=src -> q AND v_src. Pair 1 (XCDs 4-7): A=tgt -> k AND v_tgt.
// v stored transposed [(b*16+h)*64+d][1024] with t pre-permuted for attn b128 reads.
__global__ __launch_bounds__(256, 2) void proj_gemm(
    const float* __restrict__ srcF, const float* __restrict__ tgtF,
    const f16* __restrict__ qw16, const f16* __restrict__ kw16, const f16* __restrict__ vw16,
    const float* __restrict__ qb, const float* __restrict__ kb, const float* __restrict__ vb,
    f16* __restrict__ q16, f16* __restrict__ k16, f16* __restrict__ vtS, f16* __restrict__ vtT) {
  __shared__ f16 lA[2 * 128 * 32];
  __shared__ f16 lB1[2 * 128 * 32];
  __shared__ f16 lB2[2 * 128 * 32];
  const int lin = blockIdx.x;               // 512 blocks
  const int xcd = lin & 7;
  const int slot = lin >> 3;                // 0..63
  const int pr = xcd >> 2;                  // 0..1 (4 XCDs per pair)
  const int y = (xcd & 3) * 8 + (slot >> 3);  // 0..31
  const int x = slot & 7;                   // 0..7

  const float* A = pr ? tgtF : srcF;
  const f16* W1 = pr ? kw16 : qw16;
  const float* b1 = pr ? kb : qb;
  f16* O1 = pr ? k16 : q16;
  f16* O2 = pr ? vtT : vtS;
  const int row0 = y * 128;
  const int col0 = x * 128;

  const int tid = threadIdx.x;
  const int lane = tid & 63;
  const int w = tid >> 6;
  const int g = lane >> 4, c = lane & 15;
  const int wr = (w >> 1) * 64, wc = (w & 1) * 64;

  int sr[2], scol[2];
#pragma unroll
  for (int p = 0; p < 2; ++p) {
    int slt = p * 256 + tid;
    int r = slt >> 2, sph = slt & 3;
    sr[p] = r;
    scol[p] = (sph ^ ((r >> 1) & 3)) * 8;
  }
  const float* Abase = A + (size_t)row0 * 1024;
  const f16* W1base = W1 + (size_t)col0 * 1024;
  const f16* W2base = vw16 + (size_t)col0 * 1024;

  f32x4 areg[2][2];

  auto LOADA = [&](int k0) {
#pragma unroll
    for (int p = 0; p < 2; ++p) {
      const float* ap = Abase + (size_t)sr[p] * 1024 + k0 + scol[p];
      areg[p][0] = *(const f32x4*)ap;
      areg[p][1] = *(const f32x4*)(ap + 4);
    }
  };
  auto WRITEA = [&](int nb) {
#pragma unroll
    for (int p = 0; p < 2; ++p) {
      union { f16x8 v; h16x2 h[4]; } u;
      u.h[0] = __builtin_amdgcn_cvt_pkrtz(areg[p][0][0], areg[p][0][1]);
      u.h[1] = __builtin_amdgcn_cvt_pkrtz(areg[p][0][2], areg[p][0][3]);
      u.h[2] = __builtin_amdgcn_cvt_pkrtz(areg[p][1][0], areg[p][1][1]);
      u.h[3] = __builtin_amdgcn_cvt_pkrtz(areg[p][1][2], areg[p][1][3]);
      *(f16x8*)(lA + nb * (128 * 32) + (p * 256 + tid) * 8) = u.v;  // ds_write_b128
    }
  };
  auto STAGEB = [&](int nb, int k0) {
#pragma unroll
    for (int p = 0; p < 2; ++p) {
      gload_lds16(W1base + (size_t)sr[p] * 1024 + k0 + scol[p],
                  lB1 + nb * (128 * 32) + (p * 256 + w * 64) * 8);
      gload_lds16(W2base + (size_t)sr[p] * 1024 + k0 + scol[p],
                  lB2 + nb * (128 * 32) + (p * 256 + w * 64) * 8);
    }
  };

  f32x4 acc1[4][4] = {};
  f32x4 acc2[4][4] = {};

  LOADA(0);
  STAGEB(0, 0);

  for (int kt = 0; kt < 32; ++kt) {
    const int cur = kt & 1;
    asm volatile("s_waitcnt vmcnt(0)" ::: "memory");   // A regs (kt) + B lds (kt) landed
    WRITEA(cur);                                       // convert + ds_write A(kt)
    if (kt < 31) LOADA((kt + 1) * 32);                 // issue next A loads
    asm volatile("s_waitcnt lgkmcnt(0)" ::: "memory"); // A ds_writes done before barrier
    __builtin_amdgcn_s_barrier();                      // lA[cur]+lB[cur] ready block-wide
    __builtin_amdgcn_sched_barrier(0);
    if (kt < 31) STAGEB(cur ^ 1, (kt + 1) * 32);       // B(kt+1) flies under compute(kt)

    const f16* cA = lA + cur * (128 * 32);
    const f16* cB1 = lB1 + cur * (128 * 32);
    const f16* cB2 = lB2 + cur * (128 * 32);
    f16x8 af[4], bf1[4], bf2[4];
#pragma unroll
    for (int m = 0; m < 4; ++m) {
      int r = wr + m * 16 + c;
      af[m] = *(const f16x8*)(cA + r * 32 + (g ^ ((r >> 1) & 3)) * 8);
    }
#pragma unroll
    for (int n = 0; n < 4; ++n) {
      int r = wc + n * 16 + c;
      int off = r * 32 + (g ^ ((r >> 1) & 3)) * 8;
      bf1[n] = *(const f16x8*)(cB1 + off);
      bf2[n] = *(const f16x8*)(cB2 + off);
    }
    __builtin_amdgcn_s_setprio(1);
#pragma unroll
    for (int m = 0; m < 4; ++m)
#pragma unroll
      for (int n = 0; n < 4; ++n) {
        acc1[m][n] = MFMA_F16(af[m], bf1[n], acc1[m][n]);
        acc2[m][n] = MFMA_F16(af[m], bf2[n], acc2[m][n]);
      }
    __builtin_amdgcn_s_setprio(0);
  }

  // epilogue 1: q/k row-major
#pragma unroll
  for (int n = 0; n < 4; ++n) {
    int colg = col0 + wc + n * 16 + c;
    float bv = b1[colg];
#pragma unroll
    for (int m = 0; m < 4; ++m) {
      int rb = row0 + wr + m * 16 + g * 4;
#pragma unroll
      for (int r = 0; r < 4; ++r)
        O1[(size_t)(rb + r) * 1024 + colg] = (f16)(acc1[m][n][r] + bv);
    }
  }
  // epilogue 2: v transposed + t-permuted
#pragma unroll
  for (int n = 0; n < 4; ++n) {
    int colg = col0 + wc + n * 16 + c;   // = h*64 + d
    float bv = vb[colg];
#pragma unroll
    for (int m = 0; m < 4; ++m) {
      int row = row0 + wr + m * 16 + g * 4;   // token row (b*1024 + t), r = +0..3
      int bb = row >> 10, t = row & 1023;
      int tl = t & 63;
      int tp = (t & ~63) + (tl & 32) + ((tl & 12) << 1) + ((tl & 16) >> 2) + (tl & 3);
      f16x4 pk;
#pragma unroll
      for (int r = 0; r < 4; ++r) pk[r] = (f16)(acc2[m][n][r] + bv);
      *(f16x4*)(O2 + ((size_t)(bb << 10) + colg) * 1024 + tp) = pk;  // 8B store
    }
  }
}

// ---------------------------------------------------------------- output projection (f32 out)
// grid = 512: xcd = lin&7, slot = lin>>3 (0..63); y = xcd*8 + slot>>3 (0..63), x = slot&7
__global__ __launch_bounds__(256, 2) void out_gemm(
    const f16* __restrict__ opre, const f16* __restrict__ ow16,
    const float* __restrict__ ob, float* __restrict__ out) {
  __shared__ f16 lA[3 * 128 * 32];
  __shared__ f16 lB[3 * 128 * 32];
  const int lin = blockIdx.x;
  const int xcd = lin & 7;
  const int slot = lin >> 3;                // 0..63
  const int y = xcd * 8 + (slot >> 3);      // 0..63
  const int x = slot & 7;                   // 0..7
  const int row0 = y * 128;
  const int col0 = x * 128;
  f32x4 acc[4][4] = {};
  gemm_core_k1024(opre, ow16, lA, lB, acc, row0, col0);
  const int lane = threadIdx.x & 63;
  const int w = threadIdx.x >> 6;
  const int g = lane >> 4, c = lane & 15;
  const int wr = (w >> 1) * 64, wc = (w & 1) * 64;
#pragma unroll
  for (int n = 0; n < 4; ++n) {
    int colg = col0 + wc + n * 16 + c;
    float bv = ob[colg];
#pragma unroll
    for (int m = 0; m < 4; ++m) {
      int rb = row0 + wr + m * 16 + g * 4;
#pragma unroll
      for (int r = 0; r < 4; ++r)
        out[(size_t)(rb + r) * 1024 + colg] = acc[m][n][r] + bv;
    }
  }
}

// ---------------------------------------------------------------- fused 2-pass flash attention
// (round-10 proven config, reverted from the KV-128 spill disaster: KV tile 64,
//  64 q-rows/wave, swapped QK^T, no-max exp2 softmax, deferred l-reduce, XOR-swizzled
//  staging, counted pipeline, XCD decode, setprio, vf-hoist, pkrtz P-pack)
__global__ __launch_bounds__(256, 2) void attn_fwd(
    const f16* __restrict__ q16, const f16* __restrict__ k16,
    const f16* __restrict__ vtS, const f16* __restrict__ vtT,
    const int* __restrict__ smask, const int* __restrict__ tmask,
    f16* __restrict__ opre) {
  const int bid = blockIdx.x;
  const int xcd = bid & 7;
  const int idx = bid >> 3;                 // 0..63
  const int bhp = xcd * 16 + (idx >> 2);    // 0..127 (16 contiguous per XCD)
  const int qblk = idx & 3;                 // 0..3
  const int pass = bhp >> 6;
  const int bh = bhp & 63;
  const int b = bh >> 4, h = bh & 15;

  const f16* Q  = pass ? k16 : q16;
  const f16* Kt = pass ? q16 : k16;
  const f16* VT = pass ? vtS : vtT;
  const int* qmask = pass ? tmask : smask;
  const int outRowOff = pass ? 4096 : 0;

  const int tid = threadIdx.x;
  const int lane = tid & 63, wv = tid >> 6;
  const int g = lane >> 4, c = lane & 15;
  const int qrow0 = qblk * 256 + wv * 64;   // 64 q-rows per wave

  __shared__ f16 lK[2][64 * 64];
  __shared__ f16 lV[2][64 * 64];

  const size_t kbase = (size_t)b * (1024 * 1024) + h * 64;
  const size_t vbase = (size_t)bh * (64 * 1024);

  const float SC2 = 0.18033688f;  // 0.125 * log2(e)
  f16x8 qf[4][2];
#pragma unroll
  for (int m = 0; m < 4; ++m) {
    f16 sh = (f16)(qmask[b * 1024 + qrow0 + m * 16 + c] ? SC2 : 0.0f);
#pragma unroll
    for (int kc = 0; kc < 2; ++kc) {
      f16x8 v = *(const f16x8*)(Q + ((size_t)(b * 1024 + qrow0 + m * 16 + c)) * 1024 + h * 64 + kc * 32 + g * 8);
#pragma unroll
      for (int j = 0; j < 8; ++j) v[j] *= sh;
      qf[m][kc] = v;
    }
  }

  auto STAGE = [&](int nb, int t0) {
#pragma unroll
    for (int i = 0; i < 2; ++i) {
      int p = i * 256 + tid;
      int row = p >> 3;
      int u = (p & 7) ^ (row & 7);
      gload_lds16(Kt + kbase + (size_t)(t0 + row) * 1024 + u * 8, &lK[nb][(i * 256 + wv * 64) * 8]);
      gload_lds16(VT + vbase + (size_t)row * 1024 + t0 + u * 8, &lV[nb][(i * 256 + wv * 64) * 8]);
    }
  };

  f32x4 accO[4][4] = {};
  float lpart[4] = {0.0f, 0.0f, 0.0f, 0.0f};

  STAGE(0, 0);

  for (int tt = 0; tt < 16; ++tt) {
    asm volatile("s_waitcnt vmcnt(0)" ::: "memory");
    __builtin_amdgcn_s_barrier();
    __builtin_amdgcn_sched_barrier(0);
    if (tt < 15) STAGE((tt + 1) & 1, (tt + 1) * 64);
    const f16* curK = lK[tt & 1];
    const f16* curV = lV[tt & 1];

    // K fragments (A-operand)
    f16x8 kf[4][2];
#pragma unroll
    for (int n = 0; n < 4; ++n) {
      int row = n * 16 + c;
#pragma unroll
      for (int kc = 0; kc < 2; ++kc)
        kf[n][kc] = *(const f16x8*)(curK + row * 64 + (((kc * 4 + g) ^ (row & 7)) * 8));
    }

    // V fragments hoisted: issue ds_reads now, latency hides under QK^T + softmax
    f16x8 vf[4][2];
#pragma unroll
    for (int nd = 0; nd < 4; ++nd) {
      int row = nd * 16 + c;
#pragma unroll
      for (int kc = 0; kc < 2; ++kc)
        vf[nd][kc] = *(const f16x8*)(curV + row * 64 + (((kc * 4 + g) ^ (row & 7)) * 8));
    }

    f16x8 pa[4][2];
#pragma unroll
    for (int m = 0; m < 4; ++m) {
      f32x4 sc[4];
      __builtin_amdgcn_s_setprio(1);
#pragma unroll
      for (int n = 0; n < 4; ++n) {
        f32x4 z = {0.0f, 0.0f, 0.0f, 0.0f};
        z = MFMA_F16(kf[n][0], qf[m][0], z);
        sc[n] = MFMA_F16(kf[n][1], qf[m][1], z);
      }
      __builtin_amdgcn_s_setprio(0);
      float e[16];
#pragma unroll
      for (int n = 0; n < 4; ++n)
#pragma unroll
        for (int r = 0; r < 4; ++r) e[n * 4 + r] = __builtin_amdgcn_exp2f(sc[n][r]);
      float s8[8];
#pragma unroll
      for (int i = 0; i < 8; ++i) s8[i] = e[i] + e[i + 8];
      float s4[4];
#pragma unroll
      for (int i = 0; i < 4; ++i) s4[i] = s8[i] + s8[i + 4];
      lpart[m] += (s4[0] + s4[1]) + (s4[2] + s4[3]);
      union PU { f16x8 v; h16x2 h[4]; } u0, u1;
#pragma unroll
      for (int i = 0; i < 4; ++i) {
        u0.h[i] = __builtin_amdgcn_cvt_pkrtz(e[2 * i], e[2 * i + 1]);
        u1.h[i] = __builtin_amdgcn_cvt_pkrtz(e[8 + 2 * i], e[9 + 2 * i]);
      }
      pa[m][0] = u0.v;
      pa[m][1] = u1.v;
    }

    // PV: accO[m][nd] += P * V   (D rows = q_local 4g+r, cols = d_local c)
    __builtin_amdgcn_s_setprio(1);
#pragma unroll
    for (int m = 0; m < 4; ++m)
#pragma unroll
      for (int nd = 0; nd < 4; ++nd) {
        accO[m][nd] = MFMA_F16(pa[m][0], vf[nd][0], accO[m][nd]);
        accO[m][nd] = MFMA_F16(pa[m][1], vf[nd][1], accO[m][nd]);
      }
    __builtin_amdgcn_s_setprio(0);
  }

  // epilogue: complete l across lanes, then O[q][d] / l(q)
#pragma unroll
  for (int m = 0; m < 4; ++m) {
    float ls = lpart[m];
    ls += __shfl_xor(ls, 16);
    ls += __shfl_xor(ls, 32);
#pragma unroll
    for (int r = 0; r < 4; ++r) {
      float lr = __shfl(ls, 20 * g + r);
      float inv = 1.0f / lr;
      size_t orow = (size_t)(outRowOff + b * 1024 + qrow0 + m * 16 + 4 * g + r);
#pragma unroll
      for (int nd = 0; nd < 4; ++nd)
        opre[orow * 1024 + h * 64 + nd * 16 + c] = (f16)(accO[m][nd][r] * inv);
    }
  }
}

// ---------------------------------------------------------------- launcher
extern "C" void kernel_launch(void* const* d_in, const int* in_sizes, int n_in,
                              void* d_out, int out_size, void* d_ws, size_t ws_size,
                              hipStream_t stream) {
  (void)in_sizes; (void)n_in; (void)out_size; (void)ws_size;
  const float* src = (const float*)d_in[0];
  const float* tgt = (const float*)d_in[1];
  const int*   smask = (const int*)d_in[2];
  const int*   tmask = (const int*)d_in[3];
  const float* qw = (const float*)d_in[4];
  const float* qb = (const float*)d_in[5];
  const float* kw = (const float*)d_in[6];
  const float* kb = (const float*)d_in[7];
  const float* vw = (const float*)d_in[8];
  const float* vb = (const float*)d_in[9];
  const float* ow = (const float*)d_in[10];
  const float* ob = (const float*)d_in[11];
  float* out = (float*)d_out;

  f16* wsp = (f16*)d_ws;
  const size_t M4 = (size_t)4096 * 1024;
  const size_t M1 = (size_t)1024 * 1024;
  f16* opre  = wsp;                 // [0, 8M) f16
  f16* qw16  = wsp + 2 * M4;        // 8M
  f16* kw16  = qw16 + M1;           // 9M
  f16* vw16  = kw16 + M1;           // 10M
  f16* ow16  = vw16 + M1;           // 11M
  f16* q16   = ow16 + M1;           // 12M
  f16* k16   = q16 + M4;            // 16M
  f16* vtS   = k16 + M4;            // 20M
  f16* vtT   = vtS + M4;            // 24M..28M

  cvt_f32_f16<<<dim3(256, 4), 256, 0, stream>>>(qw, kw, vw, ow, qw16, kw16, vw16, ow16);
  proj_gemm<<<dim3(512), 256, 0, stream>>>(src, tgt, qw16, kw16, vw16,
                                           qb, kb, vb, q16, k16, vtS, vtT);
  attn_fwd<<<dim3(512), 256, 0, stream>>>(q16, k16, vtS, vtT, smask, tmask, opre);
  out_gemm<<<dim3(512), 256, 0, stream>>>(opre, ow16, ob, out);
}